// Round 1
// baseline (169.402 us; speedup 1.0000x reference)
//
#include <hip/hip_runtime.h>
#include <math.h>

#define NROW 4096
#define FDIM 512
#define MARGIN 1.0f
#define NLAB 16

typedef __attribute__((ext_vector_type(8))) short short8;
typedef __attribute__((ext_vector_type(4))) float floatx4;

__device__ inline unsigned short f2bf(float x) {
    unsigned u = __float_as_uint(x);
    return (unsigned short)((u + 0x7FFFu + ((u >> 16) & 1u)) >> 16);
}
__device__ inline void glds16(const unsigned short* g, unsigned short* l) {
    __builtin_amdgcn_global_load_lds(
        (const __attribute__((address_space(1))) unsigned int*)g,
        (__attribute__((address_space(3))) unsigned int*)l, 16, 0, 0);
}

// ---------------------------------------------------------------------------
// Fused prep: bf16 convert + row norms + zero rns/loss. One wave per row.
// Block NROW additionally does a 16-bucket counting sort of the labels,
// builds the group offsets, the phase-2 tile worklist, and num_pos.
// ---------------------------------------------------------------------------
__global__ __launch_bounds__(64) void prep_kernel(
    const float* __restrict__ a, const float* __restrict__ b,
    const int* __restrict__ labels,
    unsigned short* __restrict__ abf, unsigned short* __restrict__ bbf,
    float* __restrict__ na, float* __restrict__ nb,
    float* __restrict__ rns, float* __restrict__ loss,
    int* __restrict__ perm, int* __restrict__ goff,
    int* __restrict__ wl, int* __restrict__ wlmeta) {
    int row  = blockIdx.x;
    int lane = threadIdx.x;

    if (row == NROW) {
        // ---- counting sort + worklist (one 64-thread block) ----
        __shared__ int hist[NLAB], off[NLAB], cur[NLAB];
        if (lane < NLAB) hist[lane] = 0;
        __syncthreads();
        for (int i = lane; i < NROW; i += 64) atomicAdd(&hist[labels[i] & 15], 1);
        __syncthreads();
        if (lane == 0) {
            int acc = 0;
            for (int g = 0; g < NLAB; ++g) { off[g] = acc; acc += hist[g]; }
            int n = 0;
            int np = 0;
            for (int g = 0; g < NLAB; ++g) {
                goff[g] = off[g];
                int c = hist[g];
                np += c * (c - 1);
                int nt = (c + 63) >> 6;
                for (int ti = 0; ti < nt; ++ti)
                    for (int tj = 0; tj < nt; ++tj)
                        wl[n++] = (g << 12) | (ti << 6) | tj;
            }
            goff[NLAB] = NROW;
            wlmeta[0] = n;      // worklist length
            wlmeta[1] = np;     // num_pos
            wlmeta[2] = 0;      // done-counter for fused finalize
        }
        __syncthreads();
        if (lane < NLAB) cur[lane] = off[lane];
        __syncthreads();
        for (int i = lane; i < NROW; i += 64) {
            int pos = atomicAdd(&cur[labels[i] & 15], 1);
            perm[pos] = i;
        }
        return;
    }

    const float4* a4 = (const float4*)(a + (size_t)row * FDIM);
    const float4* b4 = (const float4*)(b + (size_t)row * FDIM);
    ushort4* au = (ushort4*)(abf + (size_t)row * FDIM);
    ushort4* bu = (ushort4*)(bbf + (size_t)row * FDIM);
    float sa = 0.f, sb = 0.f;
    #pragma unroll
    for (int f = lane; f < FDIM / 4; f += 64) {
        float4 va = a4[f];
        float4 vb = b4[f];
        sa += va.x * va.x + va.y * va.y + va.z * va.z + va.w * va.w;
        sb += vb.x * vb.x + vb.y * vb.y + vb.z * vb.z + vb.w * vb.w;
        ushort4 ua = { f2bf(va.x), f2bf(va.y), f2bf(va.z), f2bf(va.w) };
        ushort4 ub = { f2bf(vb.x), f2bf(vb.y), f2bf(vb.z), f2bf(vb.w) };
        au[f] = ua;
        bu[f] = ub;
    }
    #pragma unroll
    for (int o = 32; o > 0; o >>= 1) {
        sa += __shfl_down(sa, o);
        sb += __shfl_down(sb, o);
    }
    if (lane == 0) {
        na[row] = sa;
        nb[row] = sb;
        rns[row] = 0.f;
        if (row == 0) loss[0] = 0.f;
    }
}

// ---------------------------------------------------------------------------
// Negsum pass: 128x128 tile of S = b @ a^T, BK=32 double-buffered, 4 waves 2x2.
// Epilogue computes D and accumulates exp(MARGIN-D) over diff-label pairs into
// rns via atomics. NO D materialization (phase 2 recomputes the 1/16 it needs).
// ---------------------------------------------------------------------------
__global__ __launch_bounds__(256) void pass_neg(
    const unsigned short* __restrict__ abf, const unsigned short* __restrict__ bbf,
    const int* __restrict__ labels,
    const float* __restrict__ na, const float* __restrict__ nb,
    float* __restrict__ rns)
{
    // 32 KB: 2 x (As 8KB + Bs 8KB) double buffer
    __shared__ __align__(16) unsigned short arena[16384];
    __shared__ int   li_s[128], lj_s[128];
    __shared__ float nb_s[128], na_s[128];

    const int t    = threadIdx.x;
    const int lane = t & 63;
    const int w    = t >> 6;
    const int wi   = w >> 1, wj = w & 1;
    // supertile swizzle: 8x8 blocks per supertile for XCD/L2 locality
    const int bid  = blockIdx.x;
    const int sup  = bid >> 6, loc = bid & 63;
    const int by   = ((sup >> 2) << 3) | (loc >> 3);
    const int bx   = ((sup & 3) << 3) | (loc & 7);
    const int ti   = by * 128;           // b-row (i) origin
    const int tj   = bx * 128;           // a-row (j) origin
    const int lr   = lane & 15;
    const int lq   = lane >> 4;

    floatx4 acc[4][4];
    #pragma unroll
    for (int i = 0; i < 4; ++i)
        #pragma unroll
        for (int j = 0; j < 4; ++j)
            acc[i][j] = (floatx4){0.f, 0.f, 0.f, 0.f};

    if (t < 128) {
        li_s[t] = labels[ti + t];
        nb_s[t] = nb[ti + t];
    } else {
        int u = t - 128;
        lj_s[u] = labels[tj + u];
        na_s[u] = na[tj + u];
    }

    auto stage = [&](int kk, int buf) {
        unsigned short* As = arena + buf * 8192;
        unsigned short* Bs = arena + 4096 + buf * 8192;
        #pragma unroll
        for (int l = 0; l < 2; ++l) {
            int c   = t + l * 256;       // 0..511: 16B chunk id
            int row = c >> 2;
            int q   = c & 3;
            glds16(abf + (size_t)(tj + row) * FDIM + kk + q * 8, As + c * 8);
            glds16(bbf + (size_t)(ti + row) * FDIM + kk + q * 8, Bs + c * 8);
        }
    };

    stage(0, 0);
    __syncthreads();

    #pragma unroll
    for (int it = 0; it < FDIM / 32; ++it) {
        if (it < FDIM / 32 - 1) stage((it + 1) * 32, (it + 1) & 1);

        const unsigned short* As = arena + (it & 1) * 8192;
        const unsigned short* Bs = As + 4096;
        short8 af[4], bf[4];
        #pragma unroll
        for (int ri = 0; ri < 4; ++ri)
            af[ri] = *(const short8*)&Bs[(wi * 64 + ri * 16 + lr) * 32 + lq * 8];
        #pragma unroll
        for (int rj = 0; rj < 4; ++rj)
            bf[rj] = *(const short8*)&As[(wj * 64 + rj * 16 + lr) * 32 + lq * 8];
        #pragma unroll
        for (int ri = 0; ri < 4; ++ri)
            #pragma unroll
            for (int rj = 0; rj < 4; ++rj)
                acc[ri][rj] = __builtin_amdgcn_mfma_f32_16x16x32_bf16(
                    af[ri], bf[rj], acc[ri][rj], 0, 0, 0);
        __syncthreads();
    }

    // epilogue: C/D layout col = lane&15, row = quad*4 + reg
    #pragma unroll
    for (int ri = 0; ri < 4; ++ri) {
        float rs[4] = {0.f, 0.f, 0.f, 0.f};
        #pragma unroll
        for (int rj = 0; rj < 4; ++rj) {
            int   jl  = wj * 64 + rj * 16 + lr;
            float naj = na_s[jl];
            int   ljv = lj_s[jl];
            #pragma unroll
            for (int r = 0; r < 4; ++r) {
                int il = wi * 64 + ri * 16 + lq * 4 + r;
                if (li_s[il] != ljv) {
                    float dsq = nb_s[il] + naj - 2.f * acc[ri][rj][r];
                    float D   = sqrtf(fmaxf(dsq, 0.f));
                    rs[r] += __expf(MARGIN - D);
                }
            }
        }
        #pragma unroll
        for (int r = 0; r < 4; ++r) {
            #pragma unroll
            for (int o = 8; o > 0; o >>= 1) rs[r] += __shfl_down(rs[r], o, 16);
        }
        if (lr == 0) {
            #pragma unroll
            for (int r = 0; r < 4; ++r)
                atomicAdd(&rns[ti + wi * 64 + ri * 16 + lq * 4 + r], rs[r]);
        }
    }
}

// ---------------------------------------------------------------------------
// Phase-2: same-label pairs only. Worklist of (group, ti, tj) 64x64 tiles over
// label-sorted row lists; gathered-row GEMM recomputes D exactly where needed
// (~1/16 of the matrix), then J/hinge^2. Last block writes the final output.
// ---------------------------------------------------------------------------
__global__ __launch_bounds__(256) void pass2_pos(
    const unsigned short* __restrict__ abf, const unsigned short* __restrict__ bbf,
    const float* __restrict__ na, const float* __restrict__ nb,
    const float* __restrict__ rns,
    const int* __restrict__ perm, const int* __restrict__ goff,
    const int* __restrict__ wl, const int* __restrict__ wlmeta,
    float* __restrict__ loss_sum, int* __restrict__ done,
    float* __restrict__ out)
{
    __shared__ __align__(16) unsigned short arena[8192];   // 2 x (As 4KB + Bs 4KB)
    __shared__ int   rows_i[64], rows_j[64];
    __shared__ float rbi_s[64], rbj_s[64], nbi_s[64], naj_s[64];
    __shared__ float part[4];

    const int t    = threadIdx.x;
    const int lane = t & 63;
    const int w    = t >> 6;
    const int wi   = w >> 1, wj = w & 1;
    const int lr   = lane & 15;
    const int lq   = lane >> 4;
    const int nwl  = wlmeta[0];

    float local = 0.f;

    for (int item = blockIdx.x; item < nwl; item += gridDim.x) {
        __syncthreads();   // protect meta/arena from previous item's readers
        int e  = wl[item];
        int g  = e >> 12, ti = (e >> 6) & 63, tj = e & 63;
        int gb = goff[g], ge = goff[g + 1];
        int cnt = ge - gb;

        if (t < 64) {
            int idx = gb + ti * 64 + t;
            int ig  = perm[idx < ge ? idx : gb];   // pad with first row of group
            rows_i[t] = ig;
            rbi_s[t]  = rns[ig];
            nbi_s[t]  = nb[ig];
        } else if (t < 128) {
            int u   = t - 64;
            int idx = gb + tj * 64 + u;
            int jg  = perm[idx < ge ? idx : gb];
            rows_j[u] = jg;
            rbj_s[u]  = rns[jg];
            naj_s[u]  = na[jg];
        }
        __syncthreads();

        int srow_a = rows_j[t >> 2];   // a-side global row this thread stages
        int srow_b = rows_i[t >> 2];   // b-side global row this thread stages
        int q      = t & 3;

        floatx4 acc[2][2];
        #pragma unroll
        for (int i = 0; i < 2; ++i)
            #pragma unroll
            for (int j = 0; j < 2; ++j)
                acc[i][j] = (floatx4){0.f, 0.f, 0.f, 0.f};

        auto stage = [&](int kk, int buf) {
            unsigned short* As = arena + buf * 4096;
            unsigned short* Bs = As + 2048;
            glds16(abf + (size_t)srow_a * FDIM + kk + q * 8, As + t * 8);
            glds16(bbf + (size_t)srow_b * FDIM + kk + q * 8, Bs + t * 8);
        };

        stage(0, 0);
        __syncthreads();

        #pragma unroll
        for (int itk = 0; itk < FDIM / 32; ++itk) {
            if (itk < FDIM / 32 - 1) stage((itk + 1) * 32, (itk + 1) & 1);

            const unsigned short* As = arena + (itk & 1) * 4096;
            const unsigned short* Bs = As + 2048;
            short8 af[2], bf[2];
            #pragma unroll
            for (int ri = 0; ri < 2; ++ri)
                af[ri] = *(const short8*)&Bs[(wi * 32 + ri * 16 + lr) * 32 + lq * 8];
            #pragma unroll
            for (int rj = 0; rj < 2; ++rj)
                bf[rj] = *(const short8*)&As[(wj * 32 + rj * 16 + lr) * 32 + lq * 8];
            #pragma unroll
            for (int ri = 0; ri < 2; ++ri)
                #pragma unroll
                for (int rj = 0; rj < 2; ++rj)
                    acc[ri][rj] = __builtin_amdgcn_mfma_f32_16x16x32_bf16(
                        af[ri], bf[rj], acc[ri][rj], 0, 0, 0);
            __syncthreads();
        }

        // epilogue: J = log(rns_i + rns_j) + D, hinged, squared
        #pragma unroll
        for (int ri = 0; ri < 2; ++ri)
            #pragma unroll
            for (int rj = 0; rj < 2; ++rj) {
                int  jl  = wj * 32 + rj * 16 + lr;
                bool vj  = (tj * 64 + jl) < cnt;
                int  jg  = rows_j[jl];
                float nav = naj_s[jl], rbj = rbj_s[jl];
                #pragma unroll
                for (int r = 0; r < 4; ++r) {
                    int  il = wi * 32 + ri * 16 + lq * 4 + r;
                    bool vi = (ti * 64 + il) < cnt;
                    if (vi && vj && rows_i[il] != jg) {
                        float dsq = nbi_s[il] + nav - 2.f * acc[ri][rj][r];
                        float D   = sqrtf(fmaxf(dsq, 0.f));
                        float J   = __logf(rbi_s[il] + rbj) + D;
                        float h   = fmaxf(J, 0.f);
                        local += h * h;
                    }
                }
            }
    }

    #pragma unroll
    for (int o = 32; o > 0; o >>= 1) local += __shfl_down(local, o);
    if (lane == 0) part[w] = local;
    __syncthreads();
    if (t == 0) {
        atomicAdd(loss_sum, part[0] + part[1] + part[2] + part[3]);
        __threadfence();
        int old = atomicAdd(done, 1);
        if (old == (int)gridDim.x - 1) {
            __threadfence();
            float total = *(volatile float*)loss_sum;
            out[0] = total / (2.0f * (float)wlmeta[1]);
        }
    }
}

// ---------------------------------------------------------------------------
extern "C" void kernel_launch(void* const* d_in, const int* in_sizes, int n_in,
                              void* d_out, int out_size, void* d_ws, size_t ws_size,
                              hipStream_t stream) {
    const float* a      = (const float*)d_in[0];
    const float* b      = (const float*)d_in[1];
    const int*   labels = (const int*)d_in[2];
    float* out = (float*)d_out;

    // ws: abf(4MB) | bbf(4MB) | na,nb,rns,loss | perm,goff,wlmeta,wl  (~8.1MB)
    unsigned short* abf = (unsigned short*)d_ws;
    unsigned short* bbf = abf + (size_t)NROW * FDIM;
    float* fws  = (float*)(bbf + (size_t)NROW * FDIM);
    float* na   = fws;
    float* nb   = fws + NROW;
    float* rns  = fws + 2 * NROW;
    float* loss = fws + 3 * NROW;
    int* iws    = (int*)(fws + 3 * NROW + 4);
    int* perm   = iws;                 // NROW
    int* goff   = iws + NROW;          // 17
    int* wlmeta = iws + NROW + 20;     // [0]=n tiles, [1]=num_pos, [2]=done
    int* wl     = iws + NROW + 24;     // <= 4352 worst case

    prep_kernel<<<NROW + 1, 64, 0, stream>>>(a, b, labels, abf, bbf, na, nb,
                                             rns, loss, perm, goff, wl, wlmeta);
    pass_neg<<<(NROW / 128) * (NROW / 128), 256, 0, stream>>>(abf, bbf, labels,
                                                              na, nb, rns);
    pass2_pos<<<256, 256, 0, stream>>>(abf, bbf, na, nb, rns, perm, goff, wl,
                                       wlmeta, loss, &wlmeta[2], out);
}

// Round 2
// 141.582 us; speedup vs baseline: 1.1965x; 1.1965x over previous
//
#include <hip/hip_runtime.h>
#include <math.h>

#define NROW 4096
#define FDIM 512
#define MARGIN 1.0f
#define NLAB 16
#define PREP_BLK 512   // blocks 0..511 convert rows; block 512 does the sort

typedef __attribute__((ext_vector_type(8))) short short8;
typedef __attribute__((ext_vector_type(4))) float floatx4;

__device__ inline unsigned short f2bf(float x) {
    unsigned u = __float_as_uint(x);
    return (unsigned short)((u + 0x7FFFu + ((u >> 16) & 1u)) >> 16);
}
__device__ inline void glds16(const unsigned short* g, unsigned short* l) {
    __builtin_amdgcn_global_load_lds(
        (const __attribute__((address_space(1))) unsigned int*)g,
        (__attribute__((address_space(3))) unsigned int*)l, 16, 0, 0);
}

// ---------------------------------------------------------------------------
// Prep: bf16 convert + row norms + zero rns/loss.
// 512 blocks x 256 threads, 8 rows/block (32 lanes per row, 32B loads,
// 16B bf16 stores per lane). Block 512: counting sort + worklist + num_pos.
// ---------------------------------------------------------------------------
__global__ __launch_bounds__(256) void prep_kernel(
    const float* __restrict__ a, const float* __restrict__ b,
    const int* __restrict__ labels,
    unsigned short* __restrict__ abf, unsigned short* __restrict__ bbf,
    float* __restrict__ na, float* __restrict__ nb,
    float* __restrict__ rns, float* __restrict__ loss,
    int* __restrict__ perm, int* __restrict__ goff,
    int* __restrict__ wl, int* __restrict__ wlmeta) {
    const int t = threadIdx.x;

    if (blockIdx.x == PREP_BLK) {
        // ---- counting sort + worklist (one 256-thread block) ----
        __shared__ int hist[NLAB], off[NLAB], cur[NLAB];
        if (t < NLAB) hist[t] = 0;
        __syncthreads();
        for (int i = t; i < NROW; i += 256) atomicAdd(&hist[labels[i] & 15], 1);
        __syncthreads();
        if (t == 0) {
            int acc = 0;
            for (int g = 0; g < NLAB; ++g) { off[g] = acc; acc += hist[g]; }
            int n = 0;
            long long np = 0;
            for (int g = 0; g < NLAB; ++g) {
                goff[g] = off[g];
                int c = hist[g];
                np += (long long)c * (long long)(c - 1);
                int nt = (c + 63) >> 6;
                for (int ti = 0; ti < nt; ++ti)
                    for (int tj = 0; tj < nt; ++tj)
                        wl[n++] = (g << 12) | (ti << 6) | tj;
            }
            goff[NLAB] = NROW;
            wlmeta[0] = n;          // worklist length
            wlmeta[1] = (int)np;    // num_pos
            wlmeta[2] = 0;          // done-counter for fused finalize
            loss[0]   = 0.f;
        }
        __syncthreads();
        if (t < NLAB) cur[t] = off[t];
        __syncthreads();
        for (int i = t; i < NROW; i += 256) {
            int pos = atomicAdd(&cur[labels[i] & 15], 1);
            perm[pos] = i;
        }
        return;
    }

    const int grp = t >> 5;                 // 0..7: row within block
    const int ln  = t & 31;                 // lane within row-group
    const int row = blockIdx.x * 8 + grp;
    const float4* a4 = (const float4*)(a + (size_t)row * FDIM);
    const float4* b4 = (const float4*)(b + (size_t)row * FDIM);
    float sa = 0.f, sb = 0.f;
    #pragma unroll
    for (int k = 0; k < 2; ++k) {
        int f = ln * 2 + k * 64;            // float4 index, even
        float4 va0 = a4[f], va1 = a4[f + 1];
        float4 vb0 = b4[f], vb1 = b4[f + 1];
        sa += va0.x * va0.x + va0.y * va0.y + va0.z * va0.z + va0.w * va0.w
            + va1.x * va1.x + va1.y * va1.y + va1.z * va1.z + va1.w * va1.w;
        sb += vb0.x * vb0.x + vb0.y * vb0.y + vb0.z * vb0.z + vb0.w * vb0.w
            + vb1.x * vb1.x + vb1.y * vb1.y + vb1.z * vb1.z + vb1.w * vb1.w;
        short8 ua, ub;
        ua[0] = (short)f2bf(va0.x); ua[1] = (short)f2bf(va0.y);
        ua[2] = (short)f2bf(va0.z); ua[3] = (short)f2bf(va0.w);
        ua[4] = (short)f2bf(va1.x); ua[5] = (short)f2bf(va1.y);
        ua[6] = (short)f2bf(va1.z); ua[7] = (short)f2bf(va1.w);
        ub[0] = (short)f2bf(vb0.x); ub[1] = (short)f2bf(vb0.y);
        ub[2] = (short)f2bf(vb0.z); ub[3] = (short)f2bf(vb0.w);
        ub[4] = (short)f2bf(vb1.x); ub[5] = (short)f2bf(vb1.y);
        ub[6] = (short)f2bf(vb1.z); ub[7] = (short)f2bf(vb1.w);
        *(short8*)&abf[(size_t)row * FDIM + (size_t)f * 4] = ua;
        *(short8*)&bbf[(size_t)row * FDIM + (size_t)f * 4] = ub;
    }
    #pragma unroll
    for (int o = 16; o > 0; o >>= 1) {
        sa += __shfl_down(sa, o, 32);
        sb += __shfl_down(sb, o, 32);
    }
    if (ln == 0) {
        na[row] = sa;
        nb[row] = sb;
        rns[row] = 0.f;
    }
}

// ---------------------------------------------------------------------------
// Negsum pass: 128x128 tile of S = b @ a^T, BK=32 double-buffered, 4 waves 2x2.
// LDS XOR-swizzle (rule #21): dest stays linear for global_load_lds; the
// GLOBAL source chunk is permuted q ^= (row>>1)&3 and the ds_read applies the
// same XOR -> 8-way bank conflict becomes 2-way (free).
// ---------------------------------------------------------------------------
__global__ __launch_bounds__(256) void pass_neg(
    const unsigned short* __restrict__ abf, const unsigned short* __restrict__ bbf,
    const int* __restrict__ labels,
    const float* __restrict__ na, const float* __restrict__ nb,
    float* __restrict__ rns)
{
    __shared__ __align__(16) unsigned short arena[16384];   // 2 x (As 8KB + Bs 8KB)
    __shared__ int   li_s[128], lj_s[128];
    __shared__ float nb_s[128], na_s[128];

    const int t    = threadIdx.x;
    const int lane = t & 63;
    const int w    = t >> 6;
    const int wi   = w >> 1, wj = w & 1;
    const int bid  = blockIdx.x;
    const int sup  = bid >> 6, loc = bid & 63;
    const int by   = ((sup >> 2) << 3) | (loc >> 3);
    const int bx   = ((sup & 3) << 3) | (loc & 7);
    const int ti   = by * 128;           // b-row (i) origin
    const int tj   = bx * 128;           // a-row (j) origin
    const int lr   = lane & 15;
    const int lq   = lane >> 4;
    const int qe   = lq ^ ((lr >> 1) & 3);   // swizzled read chunk

    floatx4 acc[4][4];
    #pragma unroll
    for (int i = 0; i < 4; ++i)
        #pragma unroll
        for (int j = 0; j < 4; ++j)
            acc[i][j] = (floatx4){0.f, 0.f, 0.f, 0.f};

    if (t < 128) {
        li_s[t] = labels[ti + t];
        nb_s[t] = nb[ti + t];
    } else {
        int u = t - 128;
        lj_s[u] = labels[tj + u];
        na_s[u] = na[tj + u];
    }

    auto stage = [&](int kk, int buf) {
        unsigned short* As = arena + buf * 8192;
        unsigned short* Bs = arena + 4096 + buf * 8192;
        #pragma unroll
        for (int l = 0; l < 2; ++l) {
            int c   = t + l * 256;       // 0..511: 16B chunk id
            int row = c >> 2;
            int q   = c & 3;
            int qs  = q ^ ((row >> 1) & 3);   // pre-swizzled global source
            glds16(abf + (size_t)(tj + row) * FDIM + kk + qs * 8, As + c * 8);
            glds16(bbf + (size_t)(ti + row) * FDIM + kk + qs * 8, Bs + c * 8);
        }
    };

    stage(0, 0);
    __syncthreads();

    #pragma unroll
    for (int it = 0; it < FDIM / 32; ++it) {
        if (it < FDIM / 32 - 1) stage((it + 1) * 32, (it + 1) & 1);

        const unsigned short* As = arena + (it & 1) * 8192;
        const unsigned short* Bs = As + 4096;
        short8 af[4], bf[4];
        #pragma unroll
        for (int ri = 0; ri < 4; ++ri)
            af[ri] = *(const short8*)&Bs[(wi * 64 + ri * 16 + lr) * 32 + qe * 8];
        #pragma unroll
        for (int rj = 0; rj < 4; ++rj)
            bf[rj] = *(const short8*)&As[(wj * 64 + rj * 16 + lr) * 32 + qe * 8];
        #pragma unroll
        for (int ri = 0; ri < 4; ++ri)
            #pragma unroll
            for (int rj = 0; rj < 4; ++rj)
                acc[ri][rj] = __builtin_amdgcn_mfma_f32_16x16x32_bf16(
                    af[ri], bf[rj], acc[ri][rj], 0, 0, 0);
        __syncthreads();
    }

    // epilogue: C/D layout col = lane&15, row = quad*4 + reg
    #pragma unroll
    for (int ri = 0; ri < 4; ++ri) {
        float rs[4] = {0.f, 0.f, 0.f, 0.f};
        #pragma unroll
        for (int rj = 0; rj < 4; ++rj) {
            int   jl  = wj * 64 + rj * 16 + lr;
            float naj = na_s[jl];
            int   ljv = lj_s[jl];
            #pragma unroll
            for (int r = 0; r < 4; ++r) {
                int il = wi * 64 + ri * 16 + lq * 4 + r;
                if (li_s[il] != ljv) {
                    float dsq = nb_s[il] + naj - 2.f * acc[ri][rj][r];
                    float D   = sqrtf(fmaxf(dsq, 0.f));
                    rs[r] += __expf(MARGIN - D);
                }
            }
        }
        #pragma unroll
        for (int r = 0; r < 4; ++r) {
            #pragma unroll
            for (int o = 8; o > 0; o >>= 1) rs[r] += __shfl_down(rs[r], o, 16);
        }
        if (lr == 0) {
            #pragma unroll
            for (int r = 0; r < 4; ++r)
                atomicAdd(&rns[ti + wi * 64 + ri * 16 + lq * 4 + r], rs[r]);
        }
    }
}

// ---------------------------------------------------------------------------
// Phase-2: same-label 64x64 tiles, gathered-row GEMM, BK=128 (4 K-steps),
// 32KB single-buffer slab + XOR swizzle. Last block writes final output.
// ---------------------------------------------------------------------------
__global__ __launch_bounds__(256) void pass2_pos(
    const unsigned short* __restrict__ abf, const unsigned short* __restrict__ bbf,
    const float* __restrict__ na, const float* __restrict__ nb,
    const float* __restrict__ rns,
    const int* __restrict__ perm, const int* __restrict__ goff,
    const int* __restrict__ wl, const int* __restrict__ wlmeta,
    float* __restrict__ loss_sum, int* __restrict__ done,
    float* __restrict__ out)
{
    __shared__ __align__(16) unsigned short arena[16384];   // As 16KB | Bs 16KB
    __shared__ int   rows_i[64], rows_j[64];
    __shared__ float rbi_s[64], rbj_s[64], nbi_s[64], naj_s[64];
    __shared__ float part[4];

    const int t    = threadIdx.x;
    const int lane = t & 63;
    const int w    = t >> 6;
    const int wi   = w >> 1, wj = w & 1;
    const int lr   = lane & 15;
    const int lq   = lane >> 4;
    const int nwl  = wlmeta[0];

    float local = 0.f;

    for (int item = blockIdx.x; item < nwl; item += gridDim.x) {
        __syncthreads();   // previous item's readers done with meta/arena
        int e  = wl[item];
        int g  = e >> 12, ti = (e >> 6) & 63, tj = e & 63;
        int gb = goff[g], ge = goff[g + 1];
        int cnt = ge - gb;

        if (t < 64) {
            int idx = gb + ti * 64 + t;
            int ig  = perm[idx < ge ? idx : gb];   // pad with first row of group
            rows_i[t] = ig;
            rbi_s[t]  = rns[ig];
            nbi_s[t]  = nb[ig];
        } else if (t < 128) {
            int u   = t - 64;
            int idx = gb + tj * 64 + u;
            int jg  = perm[idx < ge ? idx : gb];
            rows_j[u] = jg;
            rbj_s[u]  = rns[jg];
            naj_s[u]  = na[jg];
        }
        __syncthreads();

        floatx4 acc[2][2];
        #pragma unroll
        for (int i = 0; i < 2; ++i)
            #pragma unroll
            for (int j = 0; j < 2; ++j)
                acc[i][j] = (floatx4){0.f, 0.f, 0.f, 0.f};

        // stage one BK=128 slab: per side 64 rows x 16 chunks(16B) = 16KB
        auto stage = [&](int kk) {
            #pragma unroll
            for (int l = 0; l < 4; ++l) {
                int c   = t + l * 256;           // 0..1023
                int row = c >> 4;
                int qs  = (c & 15) ^ (row & 7);  // pre-swizzled global source
                glds16(abf + (size_t)rows_j[row] * FDIM + kk + qs * 8,
                       arena + c * 8);
                glds16(bbf + (size_t)rows_i[row] * FDIM + kk + qs * 8,
                       arena + 8192 + c * 8);
            }
        };

        stage(0);
        __syncthreads();

        #pragma unroll
        for (int itk = 0; itk < 4; ++itk) {
            const unsigned short* As = arena;
            const unsigned short* Bs = arena + 8192;
            #pragma unroll
            for (int ks = 0; ks < 4; ++ks) {
                short8 af[2], bfv[2];
                #pragma unroll
                for (int ri = 0; ri < 2; ++ri) {
                    int R = wi * 32 + ri * 16 + lr;
                    af[ri] = *(const short8*)
                        &Bs[R * 128 + (((ks * 4 + lq) ^ (R & 7))) * 8];
                }
                #pragma unroll
                for (int rj = 0; rj < 2; ++rj) {
                    int R = wj * 32 + rj * 16 + lr;
                    bfv[rj] = *(const short8*)
                        &As[R * 128 + (((ks * 4 + lq) ^ (R & 7))) * 8];
                }
                #pragma unroll
                for (int ri = 0; ri < 2; ++ri)
                    #pragma unroll
                    for (int rj = 0; rj < 2; ++rj)
                        acc[ri][rj] = __builtin_amdgcn_mfma_f32_16x16x32_bf16(
                            af[ri], bfv[rj], acc[ri][rj], 0, 0, 0);
            }
            if (itk < 3) {
                __syncthreads();           // readers done with slab
                stage((itk + 1) * 128);
                __syncthreads();           // slab loads drained
            }
        }

        // epilogue: J = log(rns_i + rns_j) + D, hinged, squared
        #pragma unroll
        for (int ri = 0; ri < 2; ++ri)
            #pragma unroll
            for (int rj = 0; rj < 2; ++rj) {
                int  jl  = wj * 32 + rj * 16 + lr;
                bool vj  = (tj * 64 + jl) < cnt;
                int  jg  = rows_j[jl];
                float nav = naj_s[jl], rbj = rbj_s[jl];
                #pragma unroll
                for (int r = 0; r < 4; ++r) {
                    int  il = wi * 32 + ri * 16 + lq * 4 + r;
                    bool vi = (ti * 64 + il) < cnt;
                    if (vi && vj && rows_i[il] != jg) {
                        float dsq = nbi_s[il] + nav - 2.f * acc[ri][rj][r];
                        float D   = sqrtf(fmaxf(dsq, 0.f));
                        float J   = __logf(rbi_s[il] + rbj) + D;
                        float h   = fmaxf(J, 0.f);
                        local += h * h;
                    }
                }
            }
    }

    #pragma unroll
    for (int o = 32; o > 0; o >>= 1) local += __shfl_down(local, o);
    if (lane == 0) part[w] = local;
    __syncthreads();
    if (t == 0) {
        atomicAdd(loss_sum, part[0] + part[1] + part[2] + part[3]);
        __threadfence();
        int old = atomicAdd(done, 1);
        if (old == (int)gridDim.x - 1) {
            __threadfence();
            float total = *(volatile float*)loss_sum;
            out[0] = total / (2.0f * (float)wlmeta[1]);
        }
    }
}

// ---------------------------------------------------------------------------
extern "C" void kernel_launch(void* const* d_in, const int* in_sizes, int n_in,
                              void* d_out, int out_size, void* d_ws, size_t ws_size,
                              hipStream_t stream) {
    const float* a      = (const float*)d_in[0];
    const float* b      = (const float*)d_in[1];
    const int*   labels = (const int*)d_in[2];
    float* out = (float*)d_out;

    // ws: abf(4MB) | bbf(4MB) | na,nb,rns,loss | perm,goff,wlmeta,wl  (~8.5MB)
    unsigned short* abf = (unsigned short*)d_ws;
    unsigned short* bbf = abf + (size_t)NROW * FDIM;
    float* fws  = (float*)(bbf + (size_t)NROW * FDIM);
    float* na   = fws;
    float* nb   = fws + NROW;
    float* rns  = fws + 2 * NROW;
    float* loss = fws + 3 * NROW;
    int* iws    = (int*)(fws + 3 * NROW + 4);
    int* perm   = iws;                 // NROW
    int* goff   = iws + NROW;          // 17
    int* wlmeta = iws + NROW + 20;     // [0]=n tiles, [1]=num_pos, [2]=done
    int* wl     = iws + NROW + 24;     // <= 8192 worst case

    prep_kernel<<<PREP_BLK + 1, 256, 0, stream>>>(a, b, labels, abf, bbf,
                                                  na, nb, rns, loss,
                                                  perm, goff, wl, wlmeta);
    pass_neg<<<(NROW / 128) * (NROW / 128), 256, 0, stream>>>(abf, bbf, labels,
                                                              na, nb, rns);
    pass2_pos<<<384, 256, 0, stream>>>(abf, bbf, na, nb, rns, perm, goff, wl,
                                       wlmeta, loss, &wlmeta[2], out);
}

// Round 3
// 135.905 us; speedup vs baseline: 1.2465x; 1.0418x over previous
//
#include <hip/hip_runtime.h>
#include <math.h>

#define NROW 4096
#define FDIM 512
#define MARGIN 1.0f
#define NLAB 16
#define PREP_BLK 1024   // blocks 0..1023 convert rows; block 1024 sorts

typedef __attribute__((ext_vector_type(8))) short short8;
typedef __attribute__((ext_vector_type(4))) float floatx4;

__device__ inline unsigned short f2bf(float x) {
    unsigned u = __float_as_uint(x);
    return (unsigned short)((u + 0x7FFFu + ((u >> 16) & 1u)) >> 16);
}
__device__ inline void glds16(const unsigned short* g, unsigned short* l) {
    __builtin_amdgcn_global_load_lds(
        (const __attribute__((address_space(1))) unsigned int*)g,
        (__attribute__((address_space(3))) unsigned int*)l, 16, 0, 0);
}

// ---------------------------------------------------------------------------
// Prep: bf16 convert + row norms + zero rns/loss.
// 1024 blocks x 256 threads, 4 rows/block (full wave per row, one load round:
// 32B fp32 loads + 16B bf16 stores per lane). Block 1024: sort + worklist.
// ---------------------------------------------------------------------------
__global__ __launch_bounds__(256) void prep_kernel(
    const float* __restrict__ a, const float* __restrict__ b,
    const int* __restrict__ labels,
    unsigned short* __restrict__ abf, unsigned short* __restrict__ bbf,
    float* __restrict__ na, float* __restrict__ nb,
    float* __restrict__ rns, float* __restrict__ loss,
    int* __restrict__ perm, int* __restrict__ goff,
    int* __restrict__ wl, int* __restrict__ wlmeta) {
    const int t = threadIdx.x;

    if (blockIdx.x == PREP_BLK) {
        __shared__ int hist[NLAB], off[NLAB], cur[NLAB];
        if (t < NLAB) hist[t] = 0;
        __syncthreads();
        for (int i = t; i < NROW; i += 256) atomicAdd(&hist[labels[i] & 15], 1);
        __syncthreads();
        if (t == 0) {
            int acc = 0;
            for (int g = 0; g < NLAB; ++g) { off[g] = acc; acc += hist[g]; }
            int n = 0;
            long long np = 0;
            for (int g = 0; g < NLAB; ++g) {
                goff[g] = off[g];
                int c = hist[g];
                np += (long long)c * (long long)(c - 1);
                int nt = (c + 63) >> 6;
                for (int ti = 0; ti < nt; ++ti)
                    for (int tj = 0; tj < nt; ++tj)
                        wl[n++] = (g << 12) | (ti << 6) | tj;
            }
            goff[NLAB] = NROW;
            wlmeta[0] = n;          // worklist length
            wlmeta[1] = (int)np;    // num_pos
            wlmeta[2] = 0;          // done-counter for fused finalize
            loss[0]   = 0.f;
        }
        __syncthreads();
        if (t < NLAB) cur[t] = off[t];
        __syncthreads();
        for (int i = t; i < NROW; i += 256) {
            int pos = atomicAdd(&cur[labels[i] & 15], 1);
            perm[pos] = i;
        }
        return;
    }

    const int grp = t >> 6;                 // 0..3: row within block (wave)
    const int ln  = t & 63;                 // lane
    const int row = blockIdx.x * 4 + grp;
    const float4* a4 = (const float4*)(a + (size_t)row * FDIM);
    const float4* b4 = (const float4*)(b + (size_t)row * FDIM);
    const int f = ln * 2;                   // float4 index, even
    float4 va0 = a4[f], va1 = a4[f + 1];
    float4 vb0 = b4[f], vb1 = b4[f + 1];
    float sa = va0.x * va0.x + va0.y * va0.y + va0.z * va0.z + va0.w * va0.w
             + va1.x * va1.x + va1.y * va1.y + va1.z * va1.z + va1.w * va1.w;
    float sb = vb0.x * vb0.x + vb0.y * vb0.y + vb0.z * vb0.z + vb0.w * vb0.w
             + vb1.x * vb1.x + vb1.y * vb1.y + vb1.z * vb1.z + vb1.w * vb1.w;
    short8 ua, ub;
    ua[0] = (short)f2bf(va0.x); ua[1] = (short)f2bf(va0.y);
    ua[2] = (short)f2bf(va0.z); ua[3] = (short)f2bf(va0.w);
    ua[4] = (short)f2bf(va1.x); ua[5] = (short)f2bf(va1.y);
    ua[6] = (short)f2bf(va1.z); ua[7] = (short)f2bf(va1.w);
    ub[0] = (short)f2bf(vb0.x); ub[1] = (short)f2bf(vb0.y);
    ub[2] = (short)f2bf(vb0.z); ub[3] = (short)f2bf(vb0.w);
    ub[4] = (short)f2bf(vb1.x); ub[5] = (short)f2bf(vb1.y);
    ub[6] = (short)f2bf(vb1.z); ub[7] = (short)f2bf(vb1.w);
    *(short8*)&abf[(size_t)row * FDIM + (size_t)f * 4] = ua;
    *(short8*)&bbf[(size_t)row * FDIM + (size_t)f * 4] = ub;
    #pragma unroll
    for (int o = 32; o > 0; o >>= 1) {
        sa += __shfl_down(sa, o);
        sb += __shfl_down(sb, o);
    }
    if (ln == 0) {
        na[row] = sa;
        nb[row] = sb;
        rns[row] = 0.f;
    }
}

// ---------------------------------------------------------------------------
// Negsum pass: 256x256 tile, 256 blocks (1/CU, one round), 512 threads
// (8 waves, 2x4), BK=64 double-buffered (128KB LDS), chunk-XOR swizzle on
// both glds16 source and ds_read (rule #21). Epilogue: D + exp(M-D) over
// diff-label pairs, wj-merged in LDS, one atomicAdd per row per block.
// ---------------------------------------------------------------------------
__global__ __launch_bounds__(512, 2) void pass_neg(
    const unsigned short* __restrict__ abf, const unsigned short* __restrict__ bbf,
    const int* __restrict__ labels,
    const float* __restrict__ na, const float* __restrict__ nb,
    float* __restrict__ rns)
{
    __shared__ __align__(16) unsigned short arena[65536];  // 2 x (As 32KB + Bs 32KB)
    __shared__ float rpart[4][256];                        // per-wj row partials

    const int t    = threadIdx.x;
    const int lane = t & 63;
    const int w    = t >> 6;          // 0..7
    const int wi   = w >> 2;          // 0..1  (i-half, 128 rows)
    const int wj   = w & 3;           // 0..3  (j-quarter, 64 cols)
    const int lr   = lane & 15;
    const int lq   = lane >> 4;

    // XCD-aware bijective swizzle (256 blocks, 8 XCDs)
    const int bid = blockIdx.x;
    const int wg  = (bid & 7) * 32 + (bid >> 3);
    const int by  = wg >> 4, bx = wg & 15;
    const int ti  = by * 256;         // b-row (i) origin
    const int tj  = bx * 256;         // a-row (j) origin

    floatx4 acc[8][4];
    #pragma unroll
    for (int i = 0; i < 8; ++i)
        #pragma unroll
        for (int j = 0; j < 4; ++j)
            acc[i][j] = (floatx4){0.f, 0.f, 0.f, 0.f};

    // stage one BK=64 tile pair into buffer `buf`: per side 256 rows x 8
    // chunks(16B); LDS dest linear (lane-contiguous), global source chunk
    // pre-swizzled q ^= row&7.
    auto stage = [&](int kk, int buf) {
        unsigned short* As = arena + buf * 32768;
        unsigned short* Bs = As + 16384;
        #pragma unroll
        for (int l = 0; l < 4; ++l) {
            int c   = t + l * 512;        // 0..2047
            int row = c >> 3;
            int qs  = (c & 7) ^ (row & 7);
            glds16(abf + (size_t)(tj + row) * FDIM + kk + qs * 8, As + c * 8);
            glds16(bbf + (size_t)(ti + row) * FDIM + kk + qs * 8, Bs + c * 8);
        }
    };

    stage(0, 0);
    __syncthreads();

    for (int it = 0; it < FDIM / 64; ++it) {
        if (it < FDIM / 64 - 1) stage((it + 1) * 64, (it + 1) & 1);

        const unsigned short* As = arena + (it & 1) * 32768;
        const unsigned short* Bs = As + 16384;
        #pragma unroll
        for (int s = 0; s < 2; ++s) {
            short8 af[8], bv[4];
            #pragma unroll
            for (int ri = 0; ri < 8; ++ri) {
                int R = wi * 128 + ri * 16 + lr;
                af[ri] = *(const short8*)
                    &Bs[R * 64 + (((s * 4 + lq) ^ (R & 7))) * 8];
            }
            #pragma unroll
            for (int rj = 0; rj < 4; ++rj) {
                int R = wj * 64 + rj * 16 + lr;
                bv[rj] = *(const short8*)
                    &As[R * 64 + (((s * 4 + lq) ^ (R & 7))) * 8];
            }
            #pragma unroll
            for (int ri = 0; ri < 8; ++ri)
                #pragma unroll
                for (int rj = 0; rj < 4; ++rj)
                    acc[ri][rj] = __builtin_amdgcn_mfma_f32_16x16x32_bf16(
                        af[ri], bv[rj], acc[ri][rj], 0, 0, 0);
        }
        __syncthreads();
    }

    // epilogue: C/D layout col = lane&15, row = quad*4 + reg.
    // j-side metadata (4 cols/thread) and i-side (32 rows/thread) straight
    // from global (L1/L2-hot).
    int   ljv[4]; float najv[4];
    #pragma unroll
    for (int rj = 0; rj < 4; ++rj) {
        int jl = wj * 64 + rj * 16 + lr;
        ljv[rj]  = labels[tj + jl];
        najv[rj] = na[tj + jl];
    }
    #pragma unroll
    for (int ri = 0; ri < 8; ++ri) {
        float rs[4] = {0.f, 0.f, 0.f, 0.f};
        int liv[4]; float nbv[4];
        #pragma unroll
        for (int r = 0; r < 4; ++r) {
            int il = wi * 128 + ri * 16 + lq * 4 + r;
            liv[r] = labels[ti + il];
            nbv[r] = nb[ti + il];
        }
        #pragma unroll
        for (int rj = 0; rj < 4; ++rj)
            #pragma unroll
            for (int r = 0; r < 4; ++r) {
                if (liv[r] != ljv[rj]) {
                    float dsq = nbv[r] + najv[rj] - 2.f * acc[ri][rj][r];
                    float D   = sqrtf(fmaxf(dsq, 0.f));
                    rs[r] += __expf(MARGIN - D);
                }
            }
        #pragma unroll
        for (int r = 0; r < 4; ++r) {
            #pragma unroll
            for (int o = 8; o > 0; o >>= 1) rs[r] += __shfl_down(rs[r], o, 16);
        }
        if (lr == 0) {
            #pragma unroll
            for (int r = 0; r < 4; ++r)
                rpart[wj][wi * 128 + ri * 16 + lq * 4 + r] = rs[r];
        }
    }
    __syncthreads();
    if (t < 256) {
        float s = rpart[0][t] + rpart[1][t] + rpart[2][t] + rpart[3][t];
        atomicAdd(&rns[ti + t], s);
    }
}

// ---------------------------------------------------------------------------
// Phase-2: same-label 64x64 tiles, gathered-row GEMM, BK=128 (4 K-steps),
// 32KB single-buffer slab + XOR swizzle. Last block writes final output.
// ---------------------------------------------------------------------------
__global__ __launch_bounds__(256) void pass2_pos(
    const unsigned short* __restrict__ abf, const unsigned short* __restrict__ bbf,
    const float* __restrict__ na, const float* __restrict__ nb,
    const float* __restrict__ rns,
    const int* __restrict__ perm, const int* __restrict__ goff,
    const int* __restrict__ wl, const int* __restrict__ wlmeta,
    float* __restrict__ loss_sum, int* __restrict__ done,
    float* __restrict__ out)
{
    __shared__ __align__(16) unsigned short arena[16384];   // As 16KB | Bs 16KB
    __shared__ int   rows_i[64], rows_j[64];
    __shared__ float rbi_s[64], rbj_s[64], nbi_s[64], naj_s[64];
    __shared__ float part[4];

    const int t    = threadIdx.x;
    const int lane = t & 63;
    const int w    = t >> 6;
    const int wi   = w >> 1, wj = w & 1;
    const int lr   = lane & 15;
    const int lq   = lane >> 4;
    const int nwl  = wlmeta[0];

    float local = 0.f;

    for (int item = blockIdx.x; item < nwl; item += gridDim.x) {
        __syncthreads();   // previous item's readers done with meta/arena
        int e  = wl[item];
        int g  = e >> 12, ti = (e >> 6) & 63, tj = e & 63;
        int gb = goff[g], ge = goff[g + 1];
        int cnt = ge - gb;

        if (t < 64) {
            int idx = gb + ti * 64 + t;
            int ig  = perm[idx < ge ? idx : gb];   // pad with first row of group
            rows_i[t] = ig;
            rbi_s[t]  = rns[ig];
            nbi_s[t]  = nb[ig];
        } else if (t < 128) {
            int u   = t - 64;
            int idx = gb + tj * 64 + u;
            int jg  = perm[idx < ge ? idx : gb];
            rows_j[u] = jg;
            rbj_s[u]  = rns[jg];
            naj_s[u]  = na[jg];
        }
        __syncthreads();

        floatx4 acc[2][2];
        #pragma unroll
        for (int i = 0; i < 2; ++i)
            #pragma unroll
            for (int j = 0; j < 2; ++j)
                acc[i][j] = (floatx4){0.f, 0.f, 0.f, 0.f};

        auto stage = [&](int kk) {
            #pragma unroll
            for (int l = 0; l < 4; ++l) {
                int c   = t + l * 256;           // 0..1023
                int row = c >> 4;
                int qs  = (c & 15) ^ (row & 7);  // pre-swizzled global source
                glds16(abf + (size_t)rows_j[row] * FDIM + kk + qs * 8,
                       arena + c * 8);
                glds16(bbf + (size_t)rows_i[row] * FDIM + kk + qs * 8,
                       arena + 8192 + c * 8);
            }
        };

        stage(0);
        __syncthreads();

        #pragma unroll
        for (int itk = 0; itk < 4; ++itk) {
            const unsigned short* As = arena;
            const unsigned short* Bs = arena + 8192;
            #pragma unroll
            for (int ks = 0; ks < 4; ++ks) {
                short8 af[2], bfv[2];
                #pragma unroll
                for (int ri = 0; ri < 2; ++ri) {
                    int R = wi * 32 + ri * 16 + lr;
                    af[ri] = *(const short8*)
                        &Bs[R * 128 + (((ks * 4 + lq) ^ (R & 7))) * 8];
                }
                #pragma unroll
                for (int rj = 0; rj < 2; ++rj) {
                    int R = wj * 32 + rj * 16 + lr;
                    bfv[rj] = *(const short8*)
                        &As[R * 128 + (((ks * 4 + lq) ^ (R & 7))) * 8];
                }
                #pragma unroll
                for (int ri = 0; ri < 2; ++ri)
                    #pragma unroll
                    for (int rj = 0; rj < 2; ++rj)
                        acc[ri][rj] = __builtin_amdgcn_mfma_f32_16x16x32_bf16(
                            af[ri], bfv[rj], acc[ri][rj], 0, 0, 0);
            }
            if (itk < 3) {
                __syncthreads();           // readers done with slab
                stage((itk + 1) * 128);
                __syncthreads();           // slab loads drained
            }
        }

        // epilogue: J = log(rns_i + rns_j) + D, hinged, squared
        #pragma unroll
        for (int ri = 0; ri < 2; ++ri)
            #pragma unroll
            for (int rj = 0; rj < 2; ++rj) {
                int  jl  = wj * 32 + rj * 16 + lr;
                bool vj  = (tj * 64 + jl) < cnt;
                int  jg  = rows_j[jl];
                float nav = naj_s[jl], rbj = rbj_s[jl];
                #pragma unroll
                for (int r = 0; r < 4; ++r) {
                    int  il = wi * 32 + ri * 16 + lq * 4 + r;
                    bool vi = (ti * 64 + il) < cnt;
                    if (vi && vj && rows_i[il] != jg) {
                        float dsq = nbi_s[il] + nav - 2.f * acc[ri][rj][r];
                        float D   = sqrtf(fmaxf(dsq, 0.f));
                        float J   = __logf(rbi_s[il] + rbj) + D;
                        float h   = fmaxf(J, 0.f);
                        local += h * h;
                    }
                }
            }
    }

    #pragma unroll
    for (int o = 32; o > 0; o >>= 1) local += __shfl_down(local, o);
    if (lane == 0) part[w] = local;
    __syncthreads();
    if (t == 0) {
        atomicAdd(loss_sum, part[0] + part[1] + part[2] + part[3]);
        __threadfence();
        int old = atomicAdd(done, 1);
        if (old == (int)gridDim.x - 1) {
            __threadfence();
            float total = *(volatile float*)loss_sum;
            out[0] = total / (2.0f * (float)wlmeta[1]);
        }
    }
}

// ---------------------------------------------------------------------------
extern "C" void kernel_launch(void* const* d_in, const int* in_sizes, int n_in,
                              void* d_out, int out_size, void* d_ws, size_t ws_size,
                              hipStream_t stream) {
    const float* a      = (const float*)d_in[0];
    const float* b      = (const float*)d_in[1];
    const int*   labels = (const int*)d_in[2];
    float* out = (float*)d_out;

    // ws: abf(4MB) | bbf(4MB) | na,nb,rns,loss | perm,goff,wlmeta,wl  (~8.5MB)
    unsigned short* abf = (unsigned short*)d_ws;
    unsigned short* bbf = abf + (size_t)NROW * FDIM;
    float* fws  = (float*)(bbf + (size_t)NROW * FDIM);
    float* na   = fws;
    float* nb   = fws + NROW;
    float* rns  = fws + 2 * NROW;
    float* loss = fws + 3 * NROW;
    int* iws    = (int*)(fws + 3 * NROW + 4);
    int* perm   = iws;                 // NROW
    int* goff   = iws + NROW;          // 17
    int* wlmeta = iws + NROW + 20;     // [0]=n tiles, [1]=num_pos, [2]=done
    int* wl     = iws + NROW + 24;     // <= 8192 worst case

    prep_kernel<<<PREP_BLK + 1, 256, 0, stream>>>(a, b, labels, abf, bbf,
                                                  na, nb, rns, loss,
                                                  perm, goff, wl, wlmeta);
    pass_neg<<<(NROW / 256) * (NROW / 256), 512, 0, stream>>>(abf, bbf, labels,
                                                              na, nb, rns);
    pass2_pos<<<256, 256, 0, stream>>>(abf, bbf, na, nb, rns, perm, goff, wl,
                                       wlmeta, loss, &wlmeta[2], out);
}

// Round 5
// 130.653 us; speedup vs baseline: 1.2966x; 1.0402x over previous
//
#include <hip/hip_runtime.h>
#include <math.h>

#define NROW 4096
#define FDIM 512
#define MARGIN 1.0f
#define NLAB 16
#define PREP_BLK 1024   // blocks 0..1023 convert rows; block 1024 sorts

typedef __attribute__((ext_vector_type(8))) short short8;
typedef __attribute__((ext_vector_type(4))) float floatx4;

__device__ inline unsigned short f2bf(float x) {
    unsigned u = __float_as_uint(x);
    return (unsigned short)((u + 0x7FFFu + ((u >> 16) & 1u)) >> 16);
}
__device__ inline void glds16(const unsigned short* g, unsigned short* l) {
    __builtin_amdgcn_global_load_lds(
        (const __attribute__((address_space(1))) unsigned int*)g,
        (__attribute__((address_space(3))) unsigned int*)l, 16, 0, 0);
}
// counted-wait + barrier + schedule pin (rule #18 / m201 pattern)
#define WAIT_VM_BARRIER(N)                                          \
    do {                                                            \
        asm volatile("s_waitcnt vmcnt(" #N ")" ::: "memory");       \
        __builtin_amdgcn_s_barrier();                               \
        __builtin_amdgcn_sched_barrier(0);                          \
    } while (0)

// ---------------------------------------------------------------------------
// Prep: bf16 convert + row norms + zero rns/loss.
// 1024 blocks x 256 threads, 4 rows/block (full wave per row, one load round).
// Block 1024: counting sort + worklist + num_pos.
// ---------------------------------------------------------------------------
__global__ __launch_bounds__(256) void prep_kernel(
    const float* __restrict__ a, const float* __restrict__ b,
    const int* __restrict__ labels,
    unsigned short* __restrict__ abf, unsigned short* __restrict__ bbf,
    float* __restrict__ na, float* __restrict__ nb,
    float* __restrict__ rns, float* __restrict__ loss,
    int* __restrict__ perm, int* __restrict__ goff,
    int* __restrict__ wl, int* __restrict__ wlmeta) {
    const int t = threadIdx.x;

    if (blockIdx.x == PREP_BLK) {
        __shared__ int hist[NLAB], off[NLAB], cur[NLAB];
        if (t < NLAB) hist[t] = 0;
        __syncthreads();
        for (int i = t; i < NROW; i += 256) atomicAdd(&hist[labels[i] & 15], 1);
        __syncthreads();
        if (t == 0) {
            int acc = 0;
            for (int g = 0; g < NLAB; ++g) { off[g] = acc; acc += hist[g]; }
            int n = 0;
            long long np = 0;
            for (int g = 0; g < NLAB; ++g) {
                goff[g] = off[g];
                int c = hist[g];
                np += (long long)c * (long long)(c - 1);
                int nt = (c + 63) >> 6;
                for (int ti = 0; ti < nt; ++ti)
                    for (int tj = 0; tj < nt; ++tj)
                        wl[n++] = (g << 12) | (ti << 6) | tj;
            }
            goff[NLAB] = NROW;
            wlmeta[0] = n;          // worklist length
            wlmeta[1] = (int)np;    // num_pos
            wlmeta[2] = 0;          // done-counter for fused finalize
            loss[0]   = 0.f;
        }
        __syncthreads();
        if (t < NLAB) cur[t] = off[t];
        __syncthreads();
        for (int i = t; i < NROW; i += 256) {
            int pos = atomicAdd(&cur[labels[i] & 15], 1);
            perm[pos] = i;
        }
        return;
    }

    const int grp = t >> 6;                 // 0..3: row within block (wave)
    const int ln  = t & 63;                 // lane
    const int row = blockIdx.x * 4 + grp;
    const float4* a4 = (const float4*)(a + (size_t)row * FDIM);
    const float4* b4 = (const float4*)(b + (size_t)row * FDIM);
    const int f = ln * 2;                   // float4 index, even
    float4 va0 = a4[f], va1 = a4[f + 1];
    float4 vb0 = b4[f], vb1 = b4[f + 1];
    float sa = va0.x * va0.x + va0.y * va0.y + va0.z * va0.z + va0.w * va0.w
             + va1.x * va1.x + va1.y * va1.y + va1.z * va1.z + va1.w * va1.w;
    float sb = vb0.x * vb0.x + vb0.y * vb0.y + vb0.z * vb0.z + vb0.w * vb0.w
             + vb1.x * vb1.x + vb1.y * vb1.y + vb1.z * vb1.z + vb1.w * vb1.w;
    short8 ua, ub;
    ua[0] = (short)f2bf(va0.x); ua[1] = (short)f2bf(va0.y);
    ua[2] = (short)f2bf(va0.z); ua[3] = (short)f2bf(va0.w);
    ua[4] = (short)f2bf(va1.x); ua[5] = (short)f2bf(va1.y);
    ua[6] = (short)f2bf(va1.z); ua[7] = (short)f2bf(va1.w);
    ub[0] = (short)f2bf(vb0.x); ub[1] = (short)f2bf(vb0.y);
    ub[2] = (short)f2bf(vb0.z); ub[3] = (short)f2bf(vb0.w);
    ub[4] = (short)f2bf(vb1.x); ub[5] = (short)f2bf(vb1.y);
    ub[6] = (short)f2bf(vb1.z); ub[7] = (short)f2bf(vb1.w);
    *(short8*)&abf[(size_t)row * FDIM + (size_t)f * 4] = ua;
    *(short8*)&bbf[(size_t)row * FDIM + (size_t)f * 4] = ub;
    #pragma unroll
    for (int o = 32; o > 0; o >>= 1) {
        sa += __shfl_down(sa, o);
        sb += __shfl_down(sb, o);
    }
    if (ln == 0) {
        na[row] = sa;
        nb[row] = sb;
        rns[row] = 0.f;
    }
}

// ---------------------------------------------------------------------------
// Negsum pass: 256x256 tile, 256 blocks (1/CU), 512 threads (8 waves 2x4).
// BK=32, TRIPLE-buffered LDS (96KB), prefetch depth 2, counted vmcnt(4):
// stage(it+2)'s 4 loads stay in flight across each barrier (T4 — never
// drain to 0 in the main loop). Chunk-XOR swizzle on both glds16 source and
// ds_read (rule #21). Epilogue: D + exp(M-D) over diff-label pairs,
// wj-merged in LDS, one atomicAdd per row per block.
// ---------------------------------------------------------------------------
__global__ __launch_bounds__(512, 2) void pass_neg(
    const unsigned short* __restrict__ abf, const unsigned short* __restrict__ bbf,
    const int* __restrict__ labels,
    const float* __restrict__ na, const float* __restrict__ nb,
    float* __restrict__ rns)
{
    // 3 buffers x (As 16KB + Bs 16KB) = 96KB
    __shared__ __align__(16) unsigned short arena[49152];
    __shared__ float rpart[4][256];                        // per-wj row partials

    const int t    = threadIdx.x;
    const int lane = t & 63;
    const int w    = t >> 6;          // 0..7
    const int wi   = w >> 2;          // 0..1  (i-half, 128 rows)
    const int wj   = w & 3;           // 0..3  (j-quarter, 64 cols)
    const int lr   = lane & 15;
    const int lq   = lane >> 4;

    // XCD-aware bijective swizzle (256 blocks, 8 XCDs)
    const int bid = blockIdx.x;
    const int wg  = (bid & 7) * 32 + (bid >> 3);
    const int by  = wg >> 4, bx = wg & 15;
    const int ti  = by * 256;         // b-row (i) origin
    const int tj  = bx * 256;         // a-row (j) origin

    floatx4 acc[8][4];
    #pragma unroll
    for (int i = 0; i < 8; ++i)
        #pragma unroll
        for (int j = 0; j < 4; ++j)
            acc[i][j] = (floatx4){0.f, 0.f, 0.f, 0.f};

    // stage one BK=32 tile pair into buffer `buf`: per side 256 rows x 4
    // chunks(16B) = 16KB; 4 glds16/wave. LDS dest linear; global source
    // chunk pre-swizzled q ^= (row>>1)&3.
    auto stage = [&](int kk, int buf) {
        unsigned short* As = arena + buf * 16384;
        unsigned short* Bs = As + 8192;
        #pragma unroll
        for (int l = 0; l < 2; ++l) {
            int c   = t + l * 512;        // 0..1023
            int row = c >> 2;
            int qs  = (c & 3) ^ ((row >> 1) & 3);
            glds16(abf + (size_t)(tj + row) * FDIM + kk + qs * 8, As + c * 8);
            glds16(bbf + (size_t)(ti + row) * FDIM + kk + qs * 8, Bs + c * 8);
        }
    };

    stage(0, 0);
    stage(32, 1);
    // stage0 complete (stage1's 4 loads stay in flight), then barrier.
    WAIT_VM_BARRIER(4);

    #pragma unroll
    for (int it = 0; it < 16; ++it) {
        if (it < 14) stage((it + 2) * 32, (it + 2) % 3);

        const unsigned short* As = arena + (it % 3) * 16384;
        const unsigned short* Bs = As + 8192;
        short8 af[8], bv[4];
        #pragma unroll
        for (int ri = 0; ri < 8; ++ri) {
            int R = wi * 128 + ri * 16 + lr;
            af[ri] = *(const short8*)
                &Bs[R * 32 + ((lq ^ ((R >> 1) & 3))) * 8];
        }
        #pragma unroll
        for (int rj = 0; rj < 4; ++rj) {
            int R = wj * 64 + rj * 16 + lr;
            bv[rj] = *(const short8*)
                &As[R * 32 + ((lq ^ ((R >> 1) & 3))) * 8];
        }
        __builtin_amdgcn_s_setprio(1);
        #pragma unroll
        for (int ri = 0; ri < 8; ++ri)
            #pragma unroll
            for (int rj = 0; rj < 4; ++rj)
                acc[ri][rj] = __builtin_amdgcn_mfma_f32_16x16x32_bf16(
                    af[ri], bv[rj], acc[ri][rj], 0, 0, 0);
        __builtin_amdgcn_s_setprio(0);

        if (it < 14) {
            // stage(it+1) complete; stage(it+2)'s 4 loads remain in flight.
            WAIT_VM_BARRIER(4);
        } else if (it == 14) {
            WAIT_VM_BARRIER(0);
        }
    }

    // epilogue: C/D layout col = lane&15, row = quad*4 + reg.
    int   ljv[4]; float najv[4];
    #pragma unroll
    for (int rj = 0; rj < 4; ++rj) {
        int jl = wj * 64 + rj * 16 + lr;
        ljv[rj]  = labels[tj + jl];
        najv[rj] = na[tj + jl];
    }
    #pragma unroll
    for (int ri = 0; ri < 8; ++ri) {
        float rs[4] = {0.f, 0.f, 0.f, 0.f};
        int liv[4]; float nbv[4];
        #pragma unroll
        for (int r = 0; r < 4; ++r) {
            int il = wi * 128 + ri * 16 + lq * 4 + r;
            liv[r] = labels[ti + il];
            nbv[r] = nb[ti + il];
        }
        #pragma unroll
        for (int rj = 0; rj < 4; ++rj)
            #pragma unroll
            for (int r = 0; r < 4; ++r) {
                if (liv[r] != ljv[rj]) {
                    float dsq = nbv[r] + najv[rj] - 2.f * acc[ri][rj][r];
                    float D   = sqrtf(fmaxf(dsq, 0.f));
                    rs[r] += __expf(MARGIN - D);
                }
            }
        #pragma unroll
        for (int r = 0; r < 4; ++r) {
            #pragma unroll
            for (int o = 8; o > 0; o >>= 1) rs[r] += __shfl_down(rs[r], o, 16);
        }
        if (lr == 0) {
            #pragma unroll
            for (int r = 0; r < 4; ++r)
                rpart[wj][wi * 128 + ri * 16 + lq * 4 + r] = rs[r];
        }
    }
    __syncthreads();
    if (t < 256) {
        float s = rpart[0][t] + rpart[1][t] + rpart[2][t] + rpart[3][t];
        atomicAdd(&rns[ti + t], s);
    }
}

// ---------------------------------------------------------------------------
// Phase-2: same-label 64x64 tiles, gathered-row GEMM, BK=128 (4 K-steps),
// 2-slab issue-early/wait-late: next slab issued BEFORE compute, single
// vmcnt(0)+barrier after (stage latency hides under ds_read+MFMA; 2 blocks/CU
// cross-hide the rest). Last block writes final output.
// ---------------------------------------------------------------------------
__global__ __launch_bounds__(256) void pass2_pos(
    const unsigned short* __restrict__ abf, const unsigned short* __restrict__ bbf,
    const float* __restrict__ na, const float* __restrict__ nb,
    const float* __restrict__ rns,
    const int* __restrict__ perm, const int* __restrict__ goff,
    const int* __restrict__ wl, const int* __restrict__ wlmeta,
    float* __restrict__ loss_sum, int* __restrict__ done,
    float* __restrict__ out)
{
    // 2 slabs x (As 16KB + Bs 16KB) = 64KB
    __shared__ __align__(16) unsigned short arena[32768];
    __shared__ int   rows_i[64], rows_j[64];
    __shared__ float rbi_s[64], rbj_s[64], nbi_s[64], naj_s[64];
    __shared__ float part[4];

    const int t    = threadIdx.x;
    const int lane = t & 63;
    const int w    = t >> 6;
    const int wi   = w >> 1, wj = w & 1;
    const int lr   = lane & 15;
    const int lq   = lane >> 4;
    const int nwl  = wlmeta[0];

    float local = 0.f;

    for (int item = blockIdx.x; item < nwl; item += gridDim.x) {
        __syncthreads();   // previous item's readers done with meta/arena
        int e  = wl[item];
        int g  = e >> 12, ti = (e >> 6) & 63, tj = e & 63;
        int gb = goff[g], ge = goff[g + 1];
        int cnt = ge - gb;

        if (t < 64) {
            int idx = gb + ti * 64 + t;
            int ig  = perm[idx < ge ? idx : gb];   // pad with first row of group
            rows_i[t] = ig;
            rbi_s[t]  = rns[ig];
            nbi_s[t]  = nb[ig];
        } else if (t < 128) {
            int u   = t - 64;
            int idx = gb + tj * 64 + u;
            int jg  = perm[idx < ge ? idx : gb];
            rows_j[u] = jg;
            rbj_s[u]  = rns[jg];
            naj_s[u]  = na[jg];
        }
        __syncthreads();

        floatx4 acc[2][2];
        #pragma unroll
        for (int i = 0; i < 2; ++i)
            #pragma unroll
            for (int j = 0; j < 2; ++j)
                acc[i][j] = (floatx4){0.f, 0.f, 0.f, 0.f};

        // stage one BK=128 slab into `buf`: per side 64 rows x 16 chunks(16B)
        auto stage = [&](int kk, int buf) {
            unsigned short* As = arena + buf * 16384;
            unsigned short* Bs = As + 8192;
            #pragma unroll
            for (int l = 0; l < 4; ++l) {
                int c   = t + l * 256;           // 0..1023
                int row = c >> 4;
                int qs  = (c & 15) ^ (row & 7);  // pre-swizzled global source
                glds16(abf + (size_t)rows_j[row] * FDIM + kk + qs * 8,
                       As + c * 8);
                glds16(bbf + (size_t)rows_i[row] * FDIM + kk + qs * 8,
                       Bs + c * 8);
            }
        };

        stage(0, 0);
        WAIT_VM_BARRIER(0);

        #pragma unroll
        for (int itk = 0; itk < 4; ++itk) {
            if (itk < 3) stage((itk + 1) * 128, (itk + 1) & 1);

            const unsigned short* As = arena + (itk & 1) * 16384;
            const unsigned short* Bs = As + 8192;
            #pragma unroll
            for (int ks = 0; ks < 4; ++ks) {
                short8 af[2], bfv[2];
                #pragma unroll
                for (int ri = 0; ri < 2; ++ri) {
                    int R = wi * 32 + ri * 16 + lr;
                    af[ri] = *(const short8*)
                        &Bs[R * 128 + (((ks * 4 + lq) ^ (R & 7))) * 8];
                }
                #pragma unroll
                for (int rj = 0; rj < 2; ++rj) {
                    int R = wj * 32 + rj * 16 + lr;
                    bfv[rj] = *(const short8*)
                        &As[R * 128 + (((ks * 4 + lq) ^ (R & 7))) * 8];
                }
                #pragma unroll
                for (int ri = 0; ri < 2; ++ri)
                    #pragma unroll
                    for (int rj = 0; rj < 2; ++rj)
                        acc[ri][rj] = __builtin_amdgcn_mfma_f32_16x16x32_bf16(
                            af[ri], bfv[rj], acc[ri][rj], 0, 0, 0);
            }
            if (itk < 3) WAIT_VM_BARRIER(0);
        }

        // epilogue: J = log(rns_i + rns_j) + D, hinged, squared
        #pragma unroll
        for (int ri = 0; ri < 2; ++ri)
            #pragma unroll
            for (int rj = 0; rj < 2; ++rj) {
                int  jl  = wj * 32 + rj * 16 + lr;
                bool vj  = (tj * 64 + jl) < cnt;
                int  jg  = rows_j[jl];
                float nav = naj_s[jl], rbj = rbj_s[jl];
                #pragma unroll
                for (int r = 0; r < 4; ++r) {
                    int  il = wi * 32 + ri * 16 + lq * 4 + r;
                    bool vi = (ti * 64 + il) < cnt;
                    if (vi && vj && rows_i[il] != jg) {
                        float dsq = nbi_s[il] + nav - 2.f * acc[ri][rj][r];
                        float D   = sqrtf(fmaxf(dsq, 0.f));
                        float J   = __logf(rbi_s[il] + rbj) + D;
                        float h   = fmaxf(J, 0.f);
                        local += h * h;
                    }
                }
            }
    }

    #pragma unroll
    for (int o = 32; o > 0; o >>= 1) local += __shfl_down(local, o);
    if (lane == 0) part[w] = local;
    __syncthreads();
    if (t == 0) {
        atomicAdd(loss_sum, part[0] + part[1] + part[2] + part[3]);
        __threadfence();
        int old = atomicAdd(done, 1);
        if (old == (int)gridDim.x - 1) {
            __threadfence();
            float total = *(volatile float*)loss_sum;
            out[0] = total / (2.0f * (float)wlmeta[1]);
        }
    }
}

// ---------------------------------------------------------------------------
extern "C" void kernel_launch(void* const* d_in, const int* in_sizes, int n_in,
                              void* d_out, int out_size, void* d_ws, size_t ws_size,
                              hipStream_t stream) {
    const float* a      = (const float*)d_in[0];
    const float* b      = (const float*)d_in[1];
    const int*   labels = (const int*)d_in[2];
    float* out = (float*)d_out;

    // ws: abf(4MB) | bbf(4MB) | na,nb,rns,loss | perm,goff,wlmeta,wl  (~8.5MB)
    unsigned short* abf = (unsigned short*)d_ws;
    unsigned short* bbf = abf + (size_t)NROW * FDIM;
    float* fws  = (float*)(bbf + (size_t)NROW * FDIM);
    float* na   = fws;
    float* nb   = fws + NROW;
    float* rns  = fws + 2 * NROW;
    float* loss = fws + 3 * NROW;
    int* iws    = (int*)(fws + 3 * NROW + 4);
    int* perm   = iws;                 // NROW
    int* goff   = iws + NROW;          // 17
    int* wlmeta = iws + NROW + 20;     // [0]=n tiles, [1]=num_pos, [2]=done
    int* wl     = iws + NROW + 24;     // <= 8192 worst case

    prep_kernel<<<PREP_BLK + 1, 256, 0, stream>>>(a, b, labels, abf, bbf,
                                                  na, nb, rns, loss,
                                                  perm, goff, wl, wlmeta);
    pass_neg<<<(NROW / 256) * (NROW / 256), 512, 0, stream>>>(abf, bbf, labels,
                                                              na, nb, rns);
    pass2_pos<<<384, 256, 0, stream>>>(abf, bbf, na, nb, rns, perm, goff, wl,
                                       wlmeta, loss, &wlmeta[2], out);
}

// Round 6
// 123.237 us; speedup vs baseline: 1.3746x; 1.0602x over previous
//
#include <hip/hip_runtime.h>
#include <math.h>

#define NROW 4096
#define FDIM 512
#define MARGIN 1.0f
#define NLAB 16
#define PREP_BLK 1024   // blocks 0..1023 convert rows; block 1024 sorts

typedef __attribute__((ext_vector_type(8))) short short8;
typedef __attribute__((ext_vector_type(4))) float floatx4;

__device__ inline unsigned short f2bf(float x) {
    unsigned u = __float_as_uint(x);
    return (unsigned short)((u + 0x7FFFu + ((u >> 16) & 1u)) >> 16);
}
__device__ inline void glds16(const unsigned short* g, unsigned short* l) {
    __builtin_amdgcn_global_load_lds(
        (const __attribute__((address_space(1))) unsigned int*)g,
        (__attribute__((address_space(3))) unsigned int*)l, 16, 0, 0);
}
// counted-wait + barrier + schedule pin (rule #18 / m201 pattern)
#define WAIT_VM_BARRIER(N)                                          \
    do {                                                            \
        asm volatile("s_waitcnt vmcnt(" #N ")" ::: "memory");       \
        __builtin_amdgcn_s_barrier();                               \
        __builtin_amdgcn_sched_barrier(0);                          \
    } while (0)

// fast |v|: D = dsq * rsqrt(dsq)  (clamped so masked diagonal stays finite)
__device__ inline float fast_sqrt_pos(float dsq) {
    float c = fmaxf(dsq, 1e-20f);
    return c * __frsqrt_rn(c);
}

// ---------------------------------------------------------------------------
// Prep: bf16 convert + row norms + zero rns/loss.
// 1024 blocks x 256 threads, 4 rows/block (full wave per row, one load round).
// Block 1024: counting sort + worklist + num_pos.
// ---------------------------------------------------------------------------
__global__ __launch_bounds__(256) void prep_kernel(
    const float* __restrict__ a, const float* __restrict__ b,
    const int* __restrict__ labels,
    unsigned short* __restrict__ abf, unsigned short* __restrict__ bbf,
    float* __restrict__ na, float* __restrict__ nb,
    float* __restrict__ rns, float* __restrict__ loss,
    int* __restrict__ perm, int* __restrict__ goff,
    int* __restrict__ wl, int* __restrict__ wlmeta) {
    const int t = threadIdx.x;

    if (blockIdx.x == PREP_BLK) {
        __shared__ int hist[NLAB], off[NLAB], cur[NLAB];
        if (t < NLAB) hist[t] = 0;
        __syncthreads();
        for (int i = t; i < NROW; i += 256) atomicAdd(&hist[labels[i] & 15], 1);
        __syncthreads();
        if (t == 0) {
            int acc = 0;
            for (int g = 0; g < NLAB; ++g) { off[g] = acc; acc += hist[g]; }
            int n = 0;
            long long np = 0;
            for (int g = 0; g < NLAB; ++g) {
                goff[g] = off[g];
                int c = hist[g];
                np += (long long)c * (long long)(c - 1);
                int nt = (c + 63) >> 6;
                for (int ti = 0; ti < nt; ++ti)
                    for (int tj = 0; tj < nt; ++tj)
                        wl[n++] = (g << 12) | (ti << 6) | tj;
            }
            goff[NLAB] = NROW;
            wlmeta[0] = n;          // worklist length
            wlmeta[1] = (int)np;    // num_pos
            wlmeta[2] = 0;          // done-counter for fused finalize
            loss[0]   = 0.f;
        }
        __syncthreads();
        if (t < NLAB) cur[t] = off[t];
        __syncthreads();
        for (int i = t; i < NROW; i += 256) {
            int pos = atomicAdd(&cur[labels[i] & 15], 1);
            perm[pos] = i;
        }
        return;
    }

    const int grp = t >> 6;                 // 0..3: row within block (wave)
    const int ln  = t & 63;                 // lane
    const int row = blockIdx.x * 4 + grp;
    const float4* a4 = (const float4*)(a + (size_t)row * FDIM);
    const float4* b4 = (const float4*)(b + (size_t)row * FDIM);
    const int f = ln * 2;                   // float4 index, even
    float4 va0 = a4[f], va1 = a4[f + 1];
    float4 vb0 = b4[f], vb1 = b4[f + 1];
    float sa = va0.x * va0.x + va0.y * va0.y + va0.z * va0.z + va0.w * va0.w
             + va1.x * va1.x + va1.y * va1.y + va1.z * va1.z + va1.w * va1.w;
    float sb = vb0.x * vb0.x + vb0.y * vb0.y + vb0.z * vb0.z + vb0.w * vb0.w
             + vb1.x * vb1.x + vb1.y * vb1.y + vb1.z * vb1.z + vb1.w * vb1.w;
    short8 ua, ub;
    ua[0] = (short)f2bf(va0.x); ua[1] = (short)f2bf(va0.y);
    ua[2] = (short)f2bf(va0.z); ua[3] = (short)f2bf(va0.w);
    ua[4] = (short)f2bf(va1.x); ua[5] = (short)f2bf(va1.y);
    ua[6] = (short)f2bf(va1.z); ua[7] = (short)f2bf(va1.w);
    ub[0] = (short)f2bf(vb0.x); ub[1] = (short)f2bf(vb0.y);
    ub[2] = (short)f2bf(vb0.z); ub[3] = (short)f2bf(vb0.w);
    ub[4] = (short)f2bf(vb1.x); ub[5] = (short)f2bf(vb1.y);
    ub[6] = (short)f2bf(vb1.z); ub[7] = (short)f2bf(vb1.w);
    *(short8*)&abf[(size_t)row * FDIM + (size_t)f * 4] = ua;
    *(short8*)&bbf[(size_t)row * FDIM + (size_t)f * 4] = ub;
    #pragma unroll
    for (int o = 32; o > 0; o >>= 1) {
        sa += __shfl_down(sa, o);
        sb += __shfl_down(sb, o);
    }
    if (ln == 0) {
        na[row] = sa;
        nb[row] = sb;
        rns[row] = 0.f;
    }
}

// ---------------------------------------------------------------------------
// Negsum pass: 256x256 tile, 256 blocks (1/CU), 512 threads (8 waves 2x4).
// BK=32, QUAD-buffered LDS (128KB), prefetch depth 3, counted vmcnt(8):
// stages it+2 and it+3 stay in flight across each barrier (T4) — each
// stage gets ~3 iterations of compute to cover L2 latency. Chunk-XOR
// swizzle on both glds16 source and ds_read (rule #21). Branchless fast
// epilogue: D = dsq*rsqrt(dsq), mask-FMA; wj-merged in LDS, one atomicAdd
// per row per block.
// ---------------------------------------------------------------------------
__global__ __launch_bounds__(512, 2) void pass_neg(
    const unsigned short* __restrict__ abf, const unsigned short* __restrict__ bbf,
    const int* __restrict__ labels,
    const float* __restrict__ na, const float* __restrict__ nb,
    float* __restrict__ rns)
{
    // 4 buffers x (As 16KB + Bs 16KB) = 128KB
    __shared__ __align__(16) unsigned short arena[65536];
    __shared__ float rpart[4][256];                        // per-wj row partials

    const int t    = threadIdx.x;
    const int lane = t & 63;
    const int w    = t >> 6;          // 0..7
    const int wi   = w >> 2;          // 0..1  (i-half, 128 rows)
    const int wj   = w & 3;           // 0..3  (j-quarter, 64 cols)
    const int lr   = lane & 15;
    const int lq   = lane >> 4;

    // XCD-aware bijective swizzle (256 blocks, 8 XCDs)
    const int bid = blockIdx.x;
    const int wg  = (bid & 7) * 32 + (bid >> 3);
    const int by  = wg >> 4, bx = wg & 15;
    const int ti  = by * 256;         // b-row (i) origin
    const int tj  = bx * 256;         // a-row (j) origin

    floatx4 acc[8][4];
    #pragma unroll
    for (int i = 0; i < 8; ++i)
        #pragma unroll
        for (int j = 0; j < 4; ++j)
            acc[i][j] = (floatx4){0.f, 0.f, 0.f, 0.f};

    // stage one BK=32 tile pair into buffer `buf`: per side 256 rows x 4
    // chunks(16B) = 16KB; 4 glds16/wave. LDS dest linear; global source
    // chunk pre-swizzled q ^= (row>>1)&3.
    auto stage = [&](int kk, int buf) {
        unsigned short* As = arena + buf * 16384;
        unsigned short* Bs = As + 8192;
        #pragma unroll
        for (int l = 0; l < 2; ++l) {
            int c   = t + l * 512;        // 0..1023
            int row = c >> 2;
            int qs  = (c & 3) ^ ((row >> 1) & 3);
            glds16(abf + (size_t)(tj + row) * FDIM + kk + qs * 8, As + c * 8);
            glds16(bbf + (size_t)(ti + row) * FDIM + kk + qs * 8, Bs + c * 8);
        }
    };

    stage(0, 0);
    stage(32, 1);
    stage(64, 2);
    // stage0 complete (stages 1,2 = 8 loads stay in flight), then barrier.
    WAIT_VM_BARRIER(8);

    #pragma unroll
    for (int it = 0; it < 16; ++it) {
        if (it < 13) stage((it + 3) * 32, (it + 3) & 3);

        const unsigned short* As = arena + (it & 3) * 16384;
        const unsigned short* Bs = As + 8192;
        short8 af[8], bv[4];
        #pragma unroll
        for (int ri = 0; ri < 8; ++ri) {
            int R = wi * 128 + ri * 16 + lr;
            af[ri] = *(const short8*)
                &Bs[R * 32 + ((lq ^ ((R >> 1) & 3))) * 8];
        }
        #pragma unroll
        for (int rj = 0; rj < 4; ++rj) {
            int R = wj * 64 + rj * 16 + lr;
            bv[rj] = *(const short8*)
                &As[R * 32 + ((lq ^ ((R >> 1) & 3))) * 8];
        }
        __builtin_amdgcn_s_setprio(1);
        #pragma unroll
        for (int ri = 0; ri < 8; ++ri)
            #pragma unroll
            for (int rj = 0; rj < 4; ++rj)
                acc[ri][rj] = __builtin_amdgcn_mfma_f32_16x16x32_bf16(
                    af[ri], bv[rj], acc[ri][rj], 0, 0, 0);
        __builtin_amdgcn_s_setprio(0);

        if (it < 13) {
            // stage(it+1) complete; stages it+2,it+3 (8 loads) in flight.
            WAIT_VM_BARRIER(8);
        } else if (it == 13) {
            // outstanding: stages 14,15 (8 loads); wait stage14 complete.
            WAIT_VM_BARRIER(4);
        } else if (it == 14) {
            WAIT_VM_BARRIER(0);
        }
    }

    // epilogue: C/D layout col = lane&15, row = quad*4 + reg. Branchless.
    int   ljv[4]; float najv[4];
    #pragma unroll
    for (int rj = 0; rj < 4; ++rj) {
        int jl = wj * 64 + rj * 16 + lr;
        ljv[rj]  = labels[tj + jl];
        najv[rj] = na[tj + jl];
    }
    #pragma unroll
    for (int ri = 0; ri < 8; ++ri) {
        float rs[4] = {0.f, 0.f, 0.f, 0.f};
        int liv[4]; float nbv[4];
        #pragma unroll
        for (int r = 0; r < 4; ++r) {
            int il = wi * 128 + ri * 16 + lq * 4 + r;
            liv[r] = labels[ti + il];
            nbv[r] = nb[ti + il];
        }
        #pragma unroll
        for (int rj = 0; rj < 4; ++rj)
            #pragma unroll
            for (int r = 0; r < 4; ++r) {
                float dsq  = nbv[r] + najv[rj] - 2.f * acc[ri][rj][r];
                float D    = fast_sqrt_pos(dsq);
                float mask = (liv[r] != ljv[rj]) ? 1.f : 0.f;
                rs[r] = fmaf(mask, __expf(MARGIN - D), rs[r]);
            }
        #pragma unroll
        for (int r = 0; r < 4; ++r) {
            #pragma unroll
            for (int o = 8; o > 0; o >>= 1) rs[r] += __shfl_down(rs[r], o, 16);
        }
        if (lr == 0) {
            #pragma unroll
            for (int r = 0; r < 4; ++r)
                rpart[wj][wi * 128 + ri * 16 + lq * 4 + r] = rs[r];
        }
    }
    __syncthreads();
    if (t < 256) {
        float s = rpart[0][t] + rpart[1][t] + rpart[2][t] + rpart[3][t];
        atomicAdd(&rns[ti + t], s);
    }
}

// ---------------------------------------------------------------------------
// Phase-2: same-label 64x64 tiles, gathered-row GEMM, BK=128 (4 K-steps),
// 2-slab issue-early/wait-late: next slab issued BEFORE compute, single
// vmcnt(0)+barrier after. Last block writes final output.
// ---------------------------------------------------------------------------
__global__ __launch_bounds__(256) void pass2_pos(
    const unsigned short* __restrict__ abf, const unsigned short* __restrict__ bbf,
    const float* __restrict__ na, const float* __restrict__ nb,
    const float* __restrict__ rns,
    const int* __restrict__ perm, const int* __restrict__ goff,
    const int* __restrict__ wl, const int* __restrict__ wlmeta,
    float* __restrict__ loss_sum, int* __restrict__ done,
    float* __restrict__ out)
{
    // 2 slabs x (As 16KB + Bs 16KB) = 64KB
    __shared__ __align__(16) unsigned short arena[32768];
    __shared__ int   rows_i[64], rows_j[64];
    __shared__ float rbi_s[64], rbj_s[64], nbi_s[64], naj_s[64];
    __shared__ float part[4];

    const int t    = threadIdx.x;
    const int lane = t & 63;
    const int w    = t >> 6;
    const int wi   = w >> 1, wj = w & 1;
    const int lr   = lane & 15;
    const int lq   = lane >> 4;
    const int nwl  = wlmeta[0];

    float local = 0.f;

    for (int item = blockIdx.x; item < nwl; item += gridDim.x) {
        __syncthreads();   // previous item's readers done with meta/arena
        int e  = wl[item];
        int g  = e >> 12, ti = (e >> 6) & 63, tj = e & 63;
        int gb = goff[g], ge = goff[g + 1];
        int cnt = ge - gb;

        if (t < 64) {
            int idx = gb + ti * 64 + t;
            int ig  = perm[idx < ge ? idx : gb];   // pad with first row of group
            rows_i[t] = ig;
            rbi_s[t]  = rns[ig];
            nbi_s[t]  = nb[ig];
        } else if (t < 128) {
            int u   = t - 64;
            int idx = gb + tj * 64 + u;
            int jg  = perm[idx < ge ? idx : gb];
            rows_j[u] = jg;
            rbj_s[u]  = rns[jg];
            naj_s[u]  = na[jg];
        }
        __syncthreads();

        floatx4 acc[2][2];
        #pragma unroll
        for (int i = 0; i < 2; ++i)
            #pragma unroll
            for (int j = 0; j < 2; ++j)
                acc[i][j] = (floatx4){0.f, 0.f, 0.f, 0.f};

        // stage one BK=128 slab into `buf`: per side 64 rows x 16 chunks(16B)
        auto stage = [&](int kk, int buf) {
            unsigned short* As = arena + buf * 16384;
            unsigned short* Bs = As + 8192;
            #pragma unroll
            for (int l = 0; l < 4; ++l) {
                int c   = t + l * 256;           // 0..1023
                int row = c >> 4;
                int qs  = (c & 15) ^ (row & 7);  // pre-swizzled global source
                glds16(abf + (size_t)rows_j[row] * FDIM + kk + qs * 8,
                       As + c * 8);
                glds16(bbf + (size_t)rows_i[row] * FDIM + kk + qs * 8,
                       Bs + c * 8);
            }
        };

        stage(0, 0);
        WAIT_VM_BARRIER(0);

        #pragma unroll
        for (int itk = 0; itk < 4; ++itk) {
            if (itk < 3) stage((itk + 1) * 128, (itk + 1) & 1);

            const unsigned short* As = arena + (itk & 1) * 16384;
            const unsigned short* Bs = As + 8192;
            #pragma unroll
            for (int ks = 0; ks < 4; ++ks) {
                short8 af[2], bfv[2];
                #pragma unroll
                for (int ri = 0; ri < 2; ++ri) {
                    int R = wi * 32 + ri * 16 + lr;
                    af[ri] = *(const short8*)
                        &Bs[R * 128 + (((ks * 4 + lq) ^ (R & 7))) * 8];
                }
                #pragma unroll
                for (int rj = 0; rj < 2; ++rj) {
                    int R = wj * 32 + rj * 16 + lr;
                    bfv[rj] = *(const short8*)
                        &As[R * 128 + (((ks * 4 + lq) ^ (R & 7))) * 8];
                }
                #pragma unroll
                for (int ri = 0; ri < 2; ++ri)
                    #pragma unroll
                    for (int rj = 0; rj < 2; ++rj)
                        acc[ri][rj] = __builtin_amdgcn_mfma_f32_16x16x32_bf16(
                            af[ri], bfv[rj], acc[ri][rj], 0, 0, 0);
            }
            if (itk < 3) WAIT_VM_BARRIER(0);
        }

        // epilogue: J = log(rns_i + rns_j) + D, hinged, squared
        #pragma unroll
        for (int ri = 0; ri < 2; ++ri)
            #pragma unroll
            for (int rj = 0; rj < 2; ++rj) {
                int  jl  = wj * 32 + rj * 16 + lr;
                bool vj  = (tj * 64 + jl) < cnt;
                int  jg  = rows_j[jl];
                float nav = naj_s[jl], rbj = rbj_s[jl];
                #pragma unroll
                for (int r = 0; r < 4; ++r) {
                    int  il = wi * 32 + ri * 16 + lq * 4 + r;
                    bool vi = (ti * 64 + il) < cnt;
                    if (vi && vj && rows_i[il] != jg) {
                        float dsq = nbi_s[il] + nav - 2.f * acc[ri][rj][r];
                        float D   = fast_sqrt_pos(dsq);
                        float J   = __logf(rbi_s[il] + rbj) + D;
                        float h   = fmaxf(J, 0.f);
                        local += h * h;
                    }
                }
            }
    }

    #pragma unroll
    for (int o = 32; o > 0; o >>= 1) local += __shfl_down(local, o);
    if (lane == 0) part[w] = local;
    __syncthreads();
    if (t == 0) {
        atomicAdd(loss_sum, part[0] + part[1] + part[2] + part[3]);
        __threadfence();
        int old = atomicAdd(done, 1);
        if (old == (int)gridDim.x - 1) {
            __threadfence();
            float total = *(volatile float*)loss_sum;
            out[0] = total / (2.0f * (float)wlmeta[1]);
        }
    }
}

// ---------------------------------------------------------------------------
extern "C" void kernel_launch(void* const* d_in, const int* in_sizes, int n_in,
                              void* d_out, int out_size, void* d_ws, size_t ws_size,
                              hipStream_t stream) {
    const float* a      = (const float*)d_in[0];
    const float* b      = (const float*)d_in[1];
    const int*   labels = (const int*)d_in[2];
    float* out = (float*)d_out;

    // ws: abf(4MB) | bbf(4MB) | na,nb,rns,loss | perm,goff,wlmeta,wl  (~8.5MB)
    unsigned short* abf = (unsigned short*)d_ws;
    unsigned short* bbf = abf + (size_t)NROW * FDIM;
    float* fws  = (float*)(bbf + (size_t)NROW * FDIM);
    float* na   = fws;
    float* nb   = fws + NROW;
    float* rns  = fws + 2 * NROW;
    float* loss = fws + 3 * NROW;
    int* iws    = (int*)(fws + 3 * NROW + 4);
    int* perm   = iws;                 // NROW
    int* goff   = iws + NROW;          // 17
    int* wlmeta = iws + NROW + 20;     // [0]=n tiles, [1]=num_pos, [2]=done
    int* wl     = iws + NROW + 24;     // <= 8192 worst case

    prep_kernel<<<PREP_BLK + 1, 256, 0, stream>>>(a, b, labels, abf, bbf,
                                                  na, nb, rns, loss,
                                                  perm, goff, wl, wlmeta);
    pass_neg<<<(NROW / 256) * (NROW / 256), 512, 0, stream>>>(abf, bbf, labels,
                                                              na, nb, rns);
    pass2_pos<<<384, 256, 0, stream>>>(abf, bbf, na, nb, rns, perm, goff, wl,
                                       wlmeta, loss, &wlmeta[2], out);
}